// Round 1
// baseline (137.019 us; speedup 1.0000x reference)
//
#include <hip/hip_runtime.h>
#include <stdint.h>
#include <stddef.h>

// GCCN: h1 = relu(x @ W1); h2 = relu(geo(h1, Wg1) + b1); res = geo(h2, Wg2) + b2; out = res/|res|
// geo(h, Wg)[n,o] = sum_b sum_i h[conn[n,b], i] * Wg[b,i,o]   (gathered GEMM, K = 80*64)

typedef __attribute__((ext_vector_type(8))) short bf16x8;
typedef __attribute__((ext_vector_type(4))) float f32x4;

#define BINS 80

static __device__ __forceinline__ unsigned short f2bf(float f) {
  union { float f; unsigned int u; } c; c.f = f;
  unsigned int u = c.u;
  return (unsigned short)((u + 0x7FFFu + ((u >> 16) & 1u)) >> 16);
}

// ---------------- linear_1: h1[v][64] = relu(x[v][0:16] @ W1) as bf16 ----------------
__global__ __launch_bounds__(256) void k_lin1(const float* __restrict__ x,
                                              const float* __restrict__ W1,
                                              unsigned short* __restrict__ h1b, int n) {
  __shared__ float w1s[16 * 64];
  int tid = threadIdx.x;
  for (int i = tid; i < 16 * 64; i += 256) w1s[i] = W1[i];
  __syncthreads();
  int v = blockIdx.x * 256 + tid;
  if (v >= n) return;
  const float4* xp = (const float4*)(x + (size_t)v * 16);
  float4 x0 = xp[0], x1 = xp[1], x2 = xp[2], x3 = xp[3];
  float xr[16] = {x0.x, x0.y, x0.z, x0.w, x1.x, x1.y, x1.z, x1.w,
                  x2.x, x2.y, x2.z, x2.w, x3.x, x3.y, x3.z, x3.w};
  float acc[64];
#pragma unroll
  for (int o = 0; o < 64; ++o) acc[o] = 0.f;
#pragma unroll
  for (int i = 0; i < 16; ++i) {
    float xi = xr[i];
#pragma unroll
    for (int o = 0; o < 64; ++o) acc[o] = fmaf(xi, w1s[i * 64 + o], acc[o]);
  }
  unsigned short* hr = h1b + (size_t)v * 64;
#pragma unroll
  for (int o8 = 0; o8 < 8; ++o8) {
    bf16x8 pack;
#pragma unroll
    for (int j = 0; j < 8; ++j) pack[j] = (short)f2bf(fmaxf(acc[o8 * 8 + j], 0.f));
    *(bf16x8*)(hr + o8 * 8) = pack;
  }
}

// ------ weight image: Wg[b][i][o] f32 -> img[b] rows o (128B of bf16 i), XOR-swizzled ------
// LDS/global image byte layout: byte(o,i) = (o*128 + i*2) ^ ((o&7)<<4)
__global__ __launch_bounds__(256) void k_wimg(const float* __restrict__ Wg,
                                              unsigned char* __restrict__ img,
                                              int O, int total) {
  int t = blockIdx.x * 256 + threadIdx.x;
  if (t >= total) return;                 // total = 80 * O * 8 chunk tasks
  int c = t & 7;                          // 16B chunk within row (8 i-values)
  int o = (t >> 3) % O;
  int b = t / (O * 8);
  int boff = (o * 128 + c * 16) ^ ((o & 7) << 4);
  bf16x8 pack;
#pragma unroll
  for (int j = 0; j < 8; ++j)
    pack[j] = (short)f2bf(Wg[(size_t)(b * 64 + c * 8 + j) * O + o]);
  *(bf16x8*)(img + (size_t)b * (O * 128) + boff) = pack;
}

// ---------------- geodesic layer: gathered GEMM via MFMA 16x16x32 bf16 ----------------
// Block: 256 threads = 4 waves; wave w owns output rows [v0 + w*16, +16), all O columns.
// Per bin: Wg[b] tile (O x 64 bf16, swizzled) double-buffered in LDS via global_load_lds;
// A-fragments gathered per-lane directly from global h rows (16B contiguous per lane).
template <int OT, bool DO_NORM>
__global__ __launch_bounds__(256) void k_geo(const unsigned short* __restrict__ hin,
                                             const unsigned char* __restrict__ wimg,
                                             const float* __restrict__ bias,
                                             const int* __restrict__ conn,
                                             void* __restrict__ outp, int n) {
  constexpr int TILEB = OT * 16 * 128;   // bytes per bin weight tile (8KB / 4KB)
  __shared__ int conn_s[64 * 81];        // padded stride 81 to spread banks
  __shared__ alignas(16) unsigned char wg_s[2][TILEB];

  const int tid = threadIdx.x;
  const int lane = tid & 63;
  const int wave = tid >> 6;
  const int ln15 = lane & 15;
  const int lq = lane >> 4;              // 0..3
  const int v0 = blockIdx.x * 64;

  // stage conn rows for the 64 vertices (clamped for tail block)
  for (int idx = tid; idx < 64 * BINS; idx += 256) {
    int v = idx / BINS;
    int c = idx - v * BINS;
    int vv = v0 + v;
    if (vv > n - 1) vv = n - 1;
    conn_s[v * 81 + c] = conn[(size_t)vv * BINS + c];
  }

  auto stage = [&](int bin, int buf) {
    const unsigned char* src = wimg + (size_t)bin * TILEB + wave * (TILEB / 4) + lane * 16;
    unsigned char* dst = &wg_s[buf][wave * (TILEB / 4)];
#pragma unroll
    for (int i = 0; i < TILEB / 4096; ++i) {
      __builtin_amdgcn_global_load_lds(
          (const __attribute__((address_space(1))) unsigned int*)(const void*)(src + i * 1024),
          (__attribute__((address_space(3))) unsigned int*)(void*)(dst + i * 1024),
          16, 0, 0);
    }
  };

  // per-lane swizzled B-fragment byte offsets (constant across bins)
  int boffs[OT][2];
#pragma unroll
  for (int ot = 0; ot < OT; ++ot)
#pragma unroll
    for (int s = 0; s < 2; ++s) {
      int o = ot * 16 + ln15;
      boffs[ot][s] = (o * 128 + s * 64 + lq * 16) ^ ((o & 7) << 4);
    }

  f32x4 acc[OT];
#pragma unroll
  for (int ot = 0; ot < OT; ++ot) acc[ot] = (f32x4){0.f, 0.f, 0.f, 0.f};

  stage(0, 0);
  __syncthreads();   // also covers conn_s staging

  const int crow = (wave * 16 + ln15) * 81;
  const int koff = lq * 8;

  for (int b = 0; b < BINS; ++b) {
    int cur = b & 1;
    if (b + 1 < BINS) stage(b + 1, cur ^ 1);

    int cidx = conn_s[crow + b];
    const unsigned short* arow = hin + (size_t)cidx * 64 + koff;
    bf16x8 a0 = *(const bf16x8*)(arow);        // k = 0..31 window, this lane's 8
    bf16x8 a1 = *(const bf16x8*)(arow + 32);   // k = 32..63 window

    const unsigned char* wb = wg_s[cur];
#pragma unroll
    for (int ot = 0; ot < OT; ++ot) {
      bf16x8 b0 = *(const bf16x8*)(wb + boffs[ot][0]);
      bf16x8 b1 = *(const bf16x8*)(wb + boffs[ot][1]);
      acc[ot] = __builtin_amdgcn_mfma_f32_16x16x32_bf16(a0, b0, acc[ot], 0, 0, 0);
      acc[ot] = __builtin_amdgcn_mfma_f32_16x16x32_bf16(a1, b1, acc[ot], 0, 0, 0);
    }
    __syncthreads();  // stage(b+1) landed; everyone done reading wg_s[cur]
  }

  // epilogue: C/D layout col = lane&15, row = (lane>>4)*4 + r
  if constexpr (!DO_NORM) {
    unsigned short* hout = (unsigned short*)outp;
#pragma unroll
    for (int ot = 0; ot < OT; ++ot) {
      float bo = bias[ot * 16 + ln15];
#pragma unroll
      for (int r = 0; r < 4; ++r) {
        int v = v0 + wave * 16 + lq * 4 + r;
        if (v < n) {
          float val = fmaxf(acc[ot][r] + bo, 0.f);
          hout[(size_t)v * 64 + ot * 16 + ln15] = f2bf(val);
        }
      }
    }
  } else {
    float* outf = (float*)outp;
    float bo0 = bias[ln15];
    float bo1 = bias[16 + ln15];
#pragma unroll
    for (int r = 0; r < 4; ++r) {
      float a = acc[0][r] + bo0;
      float c2 = acc[1][r] + bo1;
      float ss = a * a + c2 * c2;
      ss += __shfl_xor(ss, 1);
      ss += __shfl_xor(ss, 2);
      ss += __shfl_xor(ss, 4);
      ss += __shfl_xor(ss, 8);
      float inv = 1.0f / sqrtf(ss);
      int v = v0 + wave * 16 + lq * 4 + r;
      if (v < n) {
        outf[(size_t)v * 32 + ln15] = a * inv;
        outf[(size_t)v * 32 + 16 + ln15] = c2 * inv;
      }
    }
  }
}

extern "C" void kernel_launch(void* const* d_in, const int* in_sizes, int n_in,
                              void* d_out, int out_size, void* d_ws, size_t ws_size,
                              hipStream_t stream) {
  const float* x   = (const float*)d_in[0];
  const float* W1  = (const float*)d_in[1];
  const float* Wg1 = (const float*)d_in[2];
  const float* b1  = (const float*)d_in[3];
  const float* Wg2 = (const float*)d_in[4];
  const float* b2  = (const float*)d_in[5];
  const int*  conn = (const int*)d_in[6];
  int n = in_sizes[0] / 16;

  unsigned char* ws = (unsigned char*)d_ws;
  size_t hb = (size_t)n * 64 * 2;                 // bf16 h table bytes
  unsigned short* h1b = (unsigned short*)(ws);
  unsigned short* h2b = (unsigned short*)(ws + hb);
  unsigned char*  w1i = ws + 2 * hb;              // 80 * 8192
  unsigned char*  w2i = ws + 2 * hb + 80 * 8192;  // 80 * 4096

  k_wimg<<<(80 * 64 * 8 + 255) / 256, 256, 0, stream>>>(Wg1, w1i, 64, 80 * 64 * 8);
  k_wimg<<<(80 * 32 * 8 + 255) / 256, 256, 0, stream>>>(Wg2, w2i, 32, 80 * 32 * 8);
  k_lin1<<<(n + 255) / 256, 256, 0, stream>>>(x, W1, h1b, n);

  int gb = (n + 63) / 64;
  k_geo<4, false><<<gb, 256, 0, stream>>>(h1b, w1i, b1, conn, (void*)h2b, n);
  k_geo<2, true><<<gb, 256, 0, stream>>>(h2b, w2i, b2, conn, d_out, n);
}